// Round 1
// baseline (911.465 us; speedup 1.0000x reference)
//
#include <hip/hip_runtime.h>

// GCN layer: out = A_coo @ (X @ W) + b
// N=100000 nodes, E=3200000 edges, D_IN=D_OUT=256.
//
// Plan:
//  1) pack W (fp32) into bf16 MFMA B-fragment layout (Wf)
//  2) GEMM: support[N,256] (bf16) = X @ W via mfma_f32_16x16x32_bf16
//  3) CSR build by dst: histogram -> 2-level exclusive scan -> cursor scatter
//  4) aggregate: one wave per node, lane owns 4 cols, fp32 accumulate, +bias
//
// MFMA 16x16x32 bf16 layouts (per guide, m89/m120-verified):
//   A frag: lane holds A[m=lane&15][k=(lane>>4)*8 + j], j=0..7
//   B frag: lane holds B[k=(lane>>4)*8 + j][n=lane&15]
//   C/D:    lane reg r holds D[row=(lane>>4)*4+r][col=lane&15]

typedef __bf16 bf16;
typedef bf16 bf16x4 __attribute__((ext_vector_type(4)));
typedef bf16 bf16x8 __attribute__((ext_vector_type(8)));
typedef float f32x4 __attribute__((ext_vector_type(4)));

#define D_DIM 256

// ---- 1) pack W[256][256] fp32 -> bf16 fragment-ordered buffer ----
// Wf index: ((kt*16 + nt)*64 + lane) * 8 + j  holds W[kt*32 + (lane>>4)*8 + j][nt*16 + (lane&15)]
__global__ void pack_w(const float* __restrict__ W, bf16* __restrict__ Wf) {
    int lane = threadIdx.x;           // 64
    int blk  = blockIdx.x;            // 128 = 8 kt * 16 nt
    int kt = blk >> 4, nt = blk & 15;
    int t = lane & 15, q = lane >> 4;
    int krow = kt * 32 + q * 8;
    int col  = nt * 16 + t;
    bf16x8 v;
#pragma unroll
    for (int j = 0; j < 8; ++j)
        v[j] = (bf16)W[(size_t)(krow + j) * D_DIM + col];
    ((bf16x8*)Wf)[(size_t)blk * 64 + lane] = v;
}

// ---- 2) GEMM: support = X @ W (bf16 out). One wave = 16 rows x 256 cols ----
__global__ void gemm_xw(const float* __restrict__ X, const bf16* __restrict__ Wf,
                        bf16* __restrict__ S, int N) {
    int wid  = blockIdx.x * 4 + (threadIdx.x >> 6);
    int base = wid * 16;
    if (base >= N) return;
    int lane = threadIdx.x & 63;
    int t = lane & 15, q = lane >> 4;

    const float* xrow = X + (size_t)(base + t) * D_DIM + q * 8;
    const bf16x8* wf = (const bf16x8*)Wf;

    f32x4 acc[16];
#pragma unroll
    for (int i = 0; i < 16; ++i) acc[i] = (f32x4){0.f, 0.f, 0.f, 0.f};

#pragma unroll
    for (int kt = 0; kt < 8; ++kt) {
        f32x4 x0 = *(const f32x4*)(xrow + kt * 32);
        f32x4 x1 = *(const f32x4*)(xrow + kt * 32 + 4);
        bf16x8 a;
        a[0] = (bf16)x0[0]; a[1] = (bf16)x0[1]; a[2] = (bf16)x0[2]; a[3] = (bf16)x0[3];
        a[4] = (bf16)x1[0]; a[5] = (bf16)x1[1]; a[6] = (bf16)x1[2]; a[7] = (bf16)x1[3];
#pragma unroll
        for (int nt = 0; nt < 16; ++nt) {
            bf16x8 bfr = wf[(size_t)(kt * 16 + nt) * 64 + lane];
            acc[nt] = __builtin_amdgcn_mfma_f32_16x16x32_bf16(a, bfr, acc[nt], 0, 0, 0);
        }
    }

#pragma unroll
    for (int nt = 0; nt < 16; ++nt) {
#pragma unroll
        for (int r = 0; r < 4; ++r) {
            S[(size_t)(base + q * 4 + r) * D_DIM + nt * 16 + t] = (bf16)acc[nt][r];
        }
    }
}

// ---- 3a) histogram of edge_dst ----
__global__ void hist_dst(const int* __restrict__ edst, int* __restrict__ counts, int E) {
    for (int e = blockIdx.x * blockDim.x + threadIdx.x; e < E; e += gridDim.x * blockDim.x)
        atomicAdd(&counts[edst[e]], 1);
}

// ---- 3b) per-block exclusive scan (1024 elems/block) ----
__global__ void scan_block(const int* __restrict__ counts, int n,
                           int* __restrict__ local_ex, int* __restrict__ bsums) {
    __shared__ int lds[1024];
    int tid = threadIdx.x;
    int g = blockIdx.x * 1024 + tid;
    int v = (g < n) ? counts[g] : 0;
    lds[tid] = v;
    __syncthreads();
    for (int d = 1; d < 1024; d <<= 1) {
        int add = (tid >= d) ? lds[tid - d] : 0;
        __syncthreads();
        lds[tid] += add;
        __syncthreads();
    }
    if (g < n) local_ex[g] = lds[tid] - v;
    if (tid == 1023) bsums[blockIdx.x] = lds[tid];
}

// ---- 3c) scan of block sums (single block, nb <= 128) ----
__global__ void scan_sums(const int* __restrict__ bsums, int nb, int* __restrict__ bex) {
    __shared__ int lds[128];
    int tid = threadIdx.x;
    int v = (tid < nb) ? bsums[tid] : 0;
    lds[tid] = v;
    __syncthreads();
    for (int d = 1; d < 128; d <<= 1) {
        int add = (tid >= d) ? lds[tid - d] : 0;
        __syncthreads();
        lds[tid] += add;
        __syncthreads();
    }
    if (tid < nb) bex[tid] = lds[tid] - v;
}

// ---- 3d) add block base; init cursor = offsets ----
__global__ void add_base(int* __restrict__ off, int* __restrict__ cursor,
                         const int* __restrict__ bex, int n) {
    int g = blockIdx.x * 1024 + threadIdx.x;
    if (g < n) {
        int v = off[g] + bex[blockIdx.x];
        off[g] = v;
        cursor[g] = v;
    }
}

// ---- 3e) scatter edges into dst-sorted order ----
__global__ void scatter_edges(const int* __restrict__ esrc, const int* __restrict__ edst,
                              const float* __restrict__ evals, int* __restrict__ cursor,
                              int* __restrict__ eS, float* __restrict__ eV, int E) {
    for (int e = blockIdx.x * blockDim.x + threadIdx.x; e < E; e += gridDim.x * blockDim.x) {
        int d = edst[e];
        int pos = atomicAdd(&cursor[d], 1);
        eS[pos] = esrc[e];
        eV[pos] = evals[e];
    }
}

// ---- 4) aggregate: one wave per node; lane owns cols [lane*4, lane*4+4) ----
__global__ void aggregate(const bf16* __restrict__ S, const int* __restrict__ off,
                          const int* __restrict__ counts, const int* __restrict__ eS,
                          const float* __restrict__ eV, const float* __restrict__ b,
                          float* __restrict__ out, int N) {
    int w = blockIdx.x * 4 + (threadIdx.x >> 6);
    if (w >= N) return;
    int lane = threadIdx.x & 63;

    f32x4 acc = ((const f32x4*)b)[lane];

    int beg = off[w];
    int end = beg + counts[w];
    for (int e = beg; e < end; ++e) {
        int s = eS[e];
        float wt = eV[e];
        bf16x4 v = *((const bf16x4*)(S + (size_t)s * D_DIM) + lane);
        acc[0] += wt * (float)v[0];
        acc[1] += wt * (float)v[1];
        acc[2] += wt * (float)v[2];
        acc[3] += wt * (float)v[3];
    }
    ((f32x4*)out)[(size_t)w * 64 + lane] = acc;
}

extern "C" void kernel_launch(void* const* d_in, const int* in_sizes, int n_in,
                              void* d_out, int out_size, void* d_ws, size_t ws_size,
                              hipStream_t stream) {
    const float* X     = (const float*)d_in[0];
    const int*   esrc  = (const int*)d_in[1];
    const int*   edst  = (const int*)d_in[2];
    const float* evals = (const float*)d_in[3];
    const float* W     = (const float*)d_in[4];
    const float* bias  = (const float*)d_in[5];
    float* out = (float*)d_out;

    const int N = in_sizes[0] / D_DIM;   // 100000
    const int E = in_sizes[1];           // 3200000

    // workspace carve-up (256B aligned)
    auto alignup = [](size_t x) { return (x + 255) & ~(size_t)255; };
    char* ws = (char*)d_ws;
    size_t o = 0;
    bf16* S      = (bf16*)(ws + o); o = alignup(o + (size_t)N * D_DIM * sizeof(bf16));
    int* counts  = (int*)(ws + o);  o = alignup(o + (size_t)N * sizeof(int));
    int* off     = (int*)(ws + o);  o = alignup(o + (size_t)N * sizeof(int));
    int* cursor  = (int*)(ws + o);  o = alignup(o + (size_t)N * sizeof(int));
    int* bsums   = (int*)(ws + o);  o = alignup(o + 1024 * sizeof(int));
    int* bex     = (int*)(ws + o);  o = alignup(o + 1024 * sizeof(int));
    int* eS      = (int*)(ws + o);  o = alignup(o + (size_t)E * sizeof(int));
    float* eV    = (float*)(ws + o); o = alignup(o + (size_t)E * sizeof(float));
    bf16* Wf     = (bf16*)(ws + o);  o = alignup(o + (size_t)D_DIM * D_DIM * sizeof(bf16));

    const int nb = (N + 1023) / 1024;        // 98 (<=128 required by scan_sums)
    const int nwaves = (N + 15) / 16;        // 6250

    hipMemsetAsync(counts, 0, (size_t)N * sizeof(int), stream);
    pack_w<<<128, 64, 0, stream>>>(W, Wf);
    gemm_xw<<<(nwaves + 3) / 4, 256, 0, stream>>>(X, Wf, S, N);
    hist_dst<<<2048, 256, 0, stream>>>(edst, counts, E);
    scan_block<<<nb, 1024, 0, stream>>>(counts, N, off, bsums);
    scan_sums<<<1, 128, 0, stream>>>(bsums, nb, bex);
    add_base<<<nb, 1024, 0, stream>>>(off, cursor, bex, N);
    scatter_edges<<<2048, 256, 0, stream>>>(esrc, edst, evals, cursor, eS, eV, E);
    aggregate<<<(N + 3) / 4, 256, 0, stream>>>(S, off, counts, eS, eV, bias, out, N);
}

// Round 2
// 847.290 us; speedup vs baseline: 1.0757x; 1.0757x over previous
//
#include <hip/hip_runtime.h>

// GCN layer: out = A_coo @ (X @ W) + b
// N=100000 nodes, E=3200000 edges, D_IN=D_OUT=256.
//
// R2 changes vs R1 (aggregate was latency-bound: 325us, VALUBusy 22%, hbm 34%):
//  - aggregate: edge loop unrolled x8, packed int2{src,val} edge records
//    -> 8 independent gathers in flight per wave (8x MLP)
//  - scatter: one 8B int2 store per edge instead of two 4B stores
//  - hist: int4 vectorized edge loads

typedef __bf16 bf16;
typedef bf16 bf16x4 __attribute__((ext_vector_type(4)));
typedef bf16 bf16x8 __attribute__((ext_vector_type(8)));
typedef float f32x4 __attribute__((ext_vector_type(4)));

#define D_DIM 256

// ---- 1) pack W[256][256] fp32 -> bf16 MFMA B-fragment layout ----
__global__ void pack_w(const float* __restrict__ W, bf16* __restrict__ Wf) {
    int lane = threadIdx.x;           // 64
    int blk  = blockIdx.x;            // 128 = 8 kt * 16 nt
    int kt = blk >> 4, nt = blk & 15;
    int t = lane & 15, q = lane >> 4;
    int krow = kt * 32 + q * 8;
    int col  = nt * 16 + t;
    bf16x8 v;
#pragma unroll
    for (int j = 0; j < 8; ++j)
        v[j] = (bf16)W[(size_t)(krow + j) * D_DIM + col];
    ((bf16x8*)Wf)[(size_t)blk * 64 + lane] = v;
}

// ---- 2) GEMM: support = X @ W (bf16 out). One wave = 16 rows x 256 cols ----
__global__ void gemm_xw(const float* __restrict__ X, const bf16* __restrict__ Wf,
                        bf16* __restrict__ S, int N) {
    int wid  = blockIdx.x * 4 + (threadIdx.x >> 6);
    int base = wid * 16;
    if (base >= N) return;
    int lane = threadIdx.x & 63;
    int t = lane & 15, q = lane >> 4;

    const float* xrow = X + (size_t)(base + t) * D_DIM + q * 8;
    const bf16x8* wf = (const bf16x8*)Wf;

    f32x4 acc[16];
#pragma unroll
    for (int i = 0; i < 16; ++i) acc[i] = (f32x4){0.f, 0.f, 0.f, 0.f};

#pragma unroll
    for (int kt = 0; kt < 8; ++kt) {
        f32x4 x0 = *(const f32x4*)(xrow + kt * 32);
        f32x4 x1 = *(const f32x4*)(xrow + kt * 32 + 4);
        bf16x8 a;
        a[0] = (bf16)x0[0]; a[1] = (bf16)x0[1]; a[2] = (bf16)x0[2]; a[3] = (bf16)x0[3];
        a[4] = (bf16)x1[0]; a[5] = (bf16)x1[1]; a[6] = (bf16)x1[2]; a[7] = (bf16)x1[3];
#pragma unroll
        for (int nt = 0; nt < 16; ++nt) {
            bf16x8 bfr = wf[(size_t)(kt * 16 + nt) * 64 + lane];
            acc[nt] = __builtin_amdgcn_mfma_f32_16x16x32_bf16(a, bfr, acc[nt], 0, 0, 0);
        }
    }

#pragma unroll
    for (int nt = 0; nt < 16; ++nt) {
#pragma unroll
        for (int r = 0; r < 4; ++r) {
            S[(size_t)(base + q * 4 + r) * D_DIM + nt * 16 + t] = (bf16)acc[nt][r];
        }
    }
}

// ---- 3a) histogram of edge_dst (int4 loads) ----
__global__ void hist_dst(const int* __restrict__ edst, int* __restrict__ counts, int E) {
    int E4 = E >> 2;
    const int4* e4 = (const int4*)edst;
    for (int i = blockIdx.x * blockDim.x + threadIdx.x; i < E4; i += gridDim.x * blockDim.x) {
        int4 d = e4[i];
        atomicAdd(&counts[d.x], 1);
        atomicAdd(&counts[d.y], 1);
        atomicAdd(&counts[d.z], 1);
        atomicAdd(&counts[d.w], 1);
    }
    // tail
    int g = blockIdx.x * blockDim.x + threadIdx.x;
    if (g < (E & 3)) atomicAdd(&counts[edst[E4 * 4 + g]], 1);
}

// ---- 3b) per-block exclusive scan (1024 elems/block) ----
__global__ void scan_block(const int* __restrict__ counts, int n,
                           int* __restrict__ local_ex, int* __restrict__ bsums) {
    __shared__ int lds[1024];
    int tid = threadIdx.x;
    int g = blockIdx.x * 1024 + tid;
    int v = (g < n) ? counts[g] : 0;
    lds[tid] = v;
    __syncthreads();
    for (int d = 1; d < 1024; d <<= 1) {
        int add = (tid >= d) ? lds[tid - d] : 0;
        __syncthreads();
        lds[tid] += add;
        __syncthreads();
    }
    if (g < n) local_ex[g] = lds[tid] - v;
    if (tid == 1023) bsums[blockIdx.x] = lds[tid];
}

// ---- 3c) scan of block sums (single block, nb <= 128) ----
__global__ void scan_sums(const int* __restrict__ bsums, int nb, int* __restrict__ bex) {
    __shared__ int lds[128];
    int tid = threadIdx.x;
    int v = (tid < nb) ? bsums[tid] : 0;
    lds[tid] = v;
    __syncthreads();
    for (int d = 1; d < 128; d <<= 1) {
        int add = (tid >= d) ? lds[tid - d] : 0;
        __syncthreads();
        lds[tid] += add;
        __syncthreads();
    }
    if (tid < nb) bex[tid] = lds[tid] - v;
}

// ---- 3d) add block base; init cursor = offsets ----
__global__ void add_base(int* __restrict__ off, int* __restrict__ cursor,
                         const int* __restrict__ bex, int n) {
    int g = blockIdx.x * 1024 + threadIdx.x;
    if (g < n) {
        int v = off[g] + bex[blockIdx.x];
        off[g] = v;
        cursor[g] = v;
    }
}

// ---- 3e) scatter edges into dst-sorted order, packed {src, val} ----
__global__ void scatter_edges(const int* __restrict__ esrc, const int* __restrict__ edst,
                              const float* __restrict__ evals, int* __restrict__ cursor,
                              int2* __restrict__ eP, int E) {
    for (int e = blockIdx.x * blockDim.x + threadIdx.x; e < E; e += gridDim.x * blockDim.x) {
        int d = edst[e];
        int pos = atomicAdd(&cursor[d], 1);
        int2 rec;
        rec.x = esrc[e];
        rec.y = __float_as_int(evals[e]);
        eP[pos] = rec;
    }
}

// ---- 4) aggregate: one wave per node; lane owns cols [lane*4, lane*4+4) ----
// Edge loop unrolled x8 for memory-level parallelism.
__global__ void __launch_bounds__(256) aggregate(
        const bf16* __restrict__ S, const int* __restrict__ off,
        const int* __restrict__ counts, const int2* __restrict__ eP,
        const float* __restrict__ b, float* __restrict__ out, int N) {
    int w = blockIdx.x * 4 + (threadIdx.x >> 6);
    if (w >= N) return;
    int lane = threadIdx.x & 63;

    f32x4 acc = ((const f32x4*)b)[lane];

    int e   = off[w];
    int end = e + counts[w];

    for (; e + 8 <= end; e += 8) {
        int2 r[8];
#pragma unroll
        for (int j = 0; j < 8; ++j) r[j] = eP[e + j];
        bf16x4 v[8];
#pragma unroll
        for (int j = 0; j < 8; ++j)
            v[j] = *((const bf16x4*)(S + (size_t)r[j].x * D_DIM) + lane);
#pragma unroll
        for (int j = 0; j < 8; ++j) {
            float wt = __int_as_float(r[j].y);
            acc[0] += wt * (float)v[j][0];
            acc[1] += wt * (float)v[j][1];
            acc[2] += wt * (float)v[j][2];
            acc[3] += wt * (float)v[j][3];
        }
    }
    for (; e < end; ++e) {
        int2 r = eP[e];
        float wt = __int_as_float(r.y);
        bf16x4 v = *((const bf16x4*)(S + (size_t)r.x * D_DIM) + lane);
        acc[0] += wt * (float)v[0];
        acc[1] += wt * (float)v[1];
        acc[2] += wt * (float)v[2];
        acc[3] += wt * (float)v[3];
    }
    ((f32x4*)out)[(size_t)w * 64 + lane] = acc;
}

extern "C" void kernel_launch(void* const* d_in, const int* in_sizes, int n_in,
                              void* d_out, int out_size, void* d_ws, size_t ws_size,
                              hipStream_t stream) {
    const float* X     = (const float*)d_in[0];
    const int*   esrc  = (const int*)d_in[1];
    const int*   edst  = (const int*)d_in[2];
    const float* evals = (const float*)d_in[3];
    const float* W     = (const float*)d_in[4];
    const float* bias  = (const float*)d_in[5];
    float* out = (float*)d_out;

    const int N = in_sizes[0] / D_DIM;   // 100000
    const int E = in_sizes[1];           // 3200000

    // workspace carve-up (256B aligned)
    auto alignup = [](size_t x) { return (x + 255) & ~(size_t)255; };
    char* ws = (char*)d_ws;
    size_t o = 0;
    bf16* S      = (bf16*)(ws + o); o = alignup(o + (size_t)N * D_DIM * sizeof(bf16));
    int* counts  = (int*)(ws + o);  o = alignup(o + (size_t)N * sizeof(int));
    int* off     = (int*)(ws + o);  o = alignup(o + (size_t)N * sizeof(int));
    int* cursor  = (int*)(ws + o);  o = alignup(o + (size_t)N * sizeof(int));
    int* bsums   = (int*)(ws + o);  o = alignup(o + 1024 * sizeof(int));
    int* bex     = (int*)(ws + o);  o = alignup(o + 1024 * sizeof(int));
    int2* eP     = (int2*)(ws + o); o = alignup(o + (size_t)E * sizeof(int2));
    bf16* Wf     = (bf16*)(ws + o); o = alignup(o + (size_t)D_DIM * D_DIM * sizeof(bf16));

    const int nb = (N + 1023) / 1024;        // 98 (<=128 required by scan_sums)
    const int nwaves = (N + 15) / 16;        // 6250

    hipMemsetAsync(counts, 0, (size_t)N * sizeof(int), stream);
    pack_w<<<128, 64, 0, stream>>>(W, Wf);
    gemm_xw<<<(nwaves + 3) / 4, 256, 0, stream>>>(X, Wf, S, N);
    hist_dst<<<2048, 256, 0, stream>>>(edst, counts, E);
    scan_block<<<nb, 1024, 0, stream>>>(counts, N, off, bsums);
    scan_sums<<<1, 128, 0, stream>>>(bsums, nb, bex);
    add_base<<<nb, 1024, 0, stream>>>(off, cursor, bex, N);
    scatter_edges<<<2048, 256, 0, stream>>>(esrc, edst, evals, cursor, eP, E);
    aggregate<<<(N + 3) / 4, 256, 0, stream>>>(S, off, counts, eP, bias, out, N);
}

// Round 3
// 676.632 us; speedup vs baseline: 1.3471x; 1.2522x over previous
//
#include <hip/hip_runtime.h>

// GCN layer: out = A_coo @ (X @ W) + b
// N=100000 nodes, E=3200000 edges, D_IN=D_OUT=256.
//
// R3 changes vs R2 (scatter_edges was 266us: returned-atomic -> dependent
// random store chain, 0.3% VALU, 0.9% HBM = pure latency):
//  - merge rank assignment into histogram: rank[e] = atomicAdd(&counts[d],1)
//    (one atomic pass total instead of two)
//  - scatter is now ATOMIC-FREE: pos = off[d] + rank[e]; fire-and-forget store
//  - both passes unrolled x4 via int4 for 4 ops in flight per thread

typedef __bf16 bf16;
typedef bf16 bf16x4 __attribute__((ext_vector_type(4)));
typedef bf16 bf16x8 __attribute__((ext_vector_type(8)));
typedef float f32x4 __attribute__((ext_vector_type(4)));

#define D_DIM 256

// ---- 1) pack W[256][256] fp32 -> bf16 MFMA B-fragment layout ----
__global__ void pack_w(const float* __restrict__ W, bf16* __restrict__ Wf) {
    int lane = threadIdx.x;           // 64
    int blk  = blockIdx.x;            // 128 = 8 kt * 16 nt
    int kt = blk >> 4, nt = blk & 15;
    int t = lane & 15, q = lane >> 4;
    int krow = kt * 32 + q * 8;
    int col  = nt * 16 + t;
    bf16x8 v;
#pragma unroll
    for (int j = 0; j < 8; ++j)
        v[j] = (bf16)W[(size_t)(krow + j) * D_DIM + col];
    ((bf16x8*)Wf)[(size_t)blk * 64 + lane] = v;
}

// ---- 2) GEMM: support = X @ W (bf16 out). One wave = 16 rows x 256 cols ----
__global__ void gemm_xw(const float* __restrict__ X, const bf16* __restrict__ Wf,
                        bf16* __restrict__ S, int N) {
    int wid  = blockIdx.x * 4 + (threadIdx.x >> 6);
    int base = wid * 16;
    if (base >= N) return;
    int lane = threadIdx.x & 63;
    int t = lane & 15, q = lane >> 4;

    const float* xrow = X + (size_t)(base + t) * D_DIM + q * 8;
    const bf16x8* wf = (const bf16x8*)Wf;

    f32x4 acc[16];
#pragma unroll
    for (int i = 0; i < 16; ++i) acc[i] = (f32x4){0.f, 0.f, 0.f, 0.f};

#pragma unroll
    for (int kt = 0; kt < 8; ++kt) {
        f32x4 x0 = *(const f32x4*)(xrow + kt * 32);
        f32x4 x1 = *(const f32x4*)(xrow + kt * 32 + 4);
        bf16x8 a;
        a[0] = (bf16)x0[0]; a[1] = (bf16)x0[1]; a[2] = (bf16)x0[2]; a[3] = (bf16)x0[3];
        a[4] = (bf16)x1[0]; a[5] = (bf16)x1[1]; a[6] = (bf16)x1[2]; a[7] = (bf16)x1[3];
#pragma unroll
        for (int nt = 0; nt < 16; ++nt) {
            bf16x8 bfr = wf[(size_t)(kt * 16 + nt) * 64 + lane];
            acc[nt] = __builtin_amdgcn_mfma_f32_16x16x32_bf16(a, bfr, acc[nt], 0, 0, 0);
        }
    }

#pragma unroll
    for (int nt = 0; nt < 16; ++nt) {
#pragma unroll
        for (int r = 0; r < 4; ++r) {
            S[(size_t)(base + q * 4 + r) * D_DIM + nt * 16 + t] = (bf16)acc[nt][r];
        }
    }
}

// ---- 3a) histogram + rank: rank[e] = old count of dst ----
__global__ void rank_edges(const int* __restrict__ edst, int* __restrict__ counts,
                           int* __restrict__ erank, int E) {
    int E4 = E >> 2;
    const int4* d4 = (const int4*)edst;
    int4* r4 = (int4*)erank;
    int gid = blockIdx.x * blockDim.x + threadIdx.x;
    int stride = gridDim.x * blockDim.x;
    for (int i = gid; i < E4; i += stride) {
        int4 d = d4[i];
        int4 r;
        r.x = atomicAdd(&counts[d.x], 1);
        r.y = atomicAdd(&counts[d.y], 1);
        r.z = atomicAdd(&counts[d.z], 1);
        r.w = atomicAdd(&counts[d.w], 1);
        r4[i] = r;
    }
    if (gid < (E & 3)) {
        int e = E4 * 4 + gid;
        erank[e] = atomicAdd(&counts[edst[e]], 1);
    }
}

// ---- 3b) per-block exclusive scan (1024 elems/block) ----
__global__ void scan_block(const int* __restrict__ counts, int n,
                           int* __restrict__ local_ex, int* __restrict__ bsums) {
    __shared__ int lds[1024];
    int tid = threadIdx.x;
    int g = blockIdx.x * 1024 + tid;
    int v = (g < n) ? counts[g] : 0;
    lds[tid] = v;
    __syncthreads();
    for (int d = 1; d < 1024; d <<= 1) {
        int add = (tid >= d) ? lds[tid - d] : 0;
        __syncthreads();
        lds[tid] += add;
        __syncthreads();
    }
    if (g < n) local_ex[g] = lds[tid] - v;
    if (tid == 1023) bsums[blockIdx.x] = lds[tid];
}

// ---- 3c) scan of block sums (single block, nb <= 128) ----
__global__ void scan_sums(const int* __restrict__ bsums, int nb, int* __restrict__ bex) {
    __shared__ int lds[128];
    int tid = threadIdx.x;
    int v = (tid < nb) ? bsums[tid] : 0;
    lds[tid] = v;
    __syncthreads();
    for (int d = 1; d < 128; d <<= 1) {
        int add = (tid >= d) ? lds[tid - d] : 0;
        __syncthreads();
        lds[tid] += add;
        __syncthreads();
    }
    if (tid < nb) bex[tid] = lds[tid] - v;
}

// ---- 3d) add block base ----
__global__ void add_base(int* __restrict__ off, const int* __restrict__ bex, int n) {
    int g = blockIdx.x * 1024 + threadIdx.x;
    if (g < n) off[g] += bex[blockIdx.x];
}

// ---- 3e) scatter edges (ATOMIC-FREE): pos = off[dst] + rank ----
__global__ void scatter_edges(const int* __restrict__ esrc, const int* __restrict__ edst,
                              const float* __restrict__ evals, const int* __restrict__ erank,
                              const int* __restrict__ off, int2* __restrict__ eP, int E) {
    int E4 = E >> 2;
    const int4* s4 = (const int4*)esrc;
    const int4* d4 = (const int4*)edst;
    const float4* v4 = (const float4*)evals;
    const int4* r4 = (const int4*)erank;
    int gid = blockIdx.x * blockDim.x + threadIdx.x;
    int stride = gridDim.x * blockDim.x;
    for (int i = gid; i < E4; i += stride) {
        int4 s = s4[i];
        int4 d = d4[i];
        int4 r = r4[i];
        float4 v = v4[i];
        int2 p0 = {s.x, __float_as_int(v.x)};
        int2 p1 = {s.y, __float_as_int(v.y)};
        int2 p2 = {s.z, __float_as_int(v.z)};
        int2 p3 = {s.w, __float_as_int(v.w)};
        eP[off[d.x] + r.x] = p0;
        eP[off[d.y] + r.y] = p1;
        eP[off[d.z] + r.z] = p2;
        eP[off[d.w] + r.w] = p3;
    }
    if (gid < (E & 3)) {
        int e = E4 * 4 + gid;
        int2 p = {esrc[e], __float_as_int(evals[e])};
        eP[off[edst[e]] + erank[e]] = p;
    }
}

// ---- 4) aggregate: one wave per node; lane owns cols [lane*4, lane*4+4) ----
// Edge loop unrolled x8 for memory-level parallelism.
__global__ void __launch_bounds__(256) aggregate(
        const bf16* __restrict__ S, const int* __restrict__ off,
        const int* __restrict__ counts, const int2* __restrict__ eP,
        const float* __restrict__ b, float* __restrict__ out, int N) {
    int w = blockIdx.x * 4 + (threadIdx.x >> 6);
    if (w >= N) return;
    int lane = threadIdx.x & 63;

    f32x4 acc = ((const f32x4*)b)[lane];

    int e   = off[w];
    int end = e + counts[w];

    for (; e + 8 <= end; e += 8) {
        int2 r[8];
#pragma unroll
        for (int j = 0; j < 8; ++j) r[j] = eP[e + j];
        bf16x4 v[8];
#pragma unroll
        for (int j = 0; j < 8; ++j)
            v[j] = *((const bf16x4*)(S + (size_t)r[j].x * D_DIM) + lane);
#pragma unroll
        for (int j = 0; j < 8; ++j) {
            float wt = __int_as_float(r[j].y);
            acc[0] += wt * (float)v[j][0];
            acc[1] += wt * (float)v[j][1];
            acc[2] += wt * (float)v[j][2];
            acc[3] += wt * (float)v[j][3];
        }
    }
    for (; e < end; ++e) {
        int2 r = eP[e];
        float wt = __int_as_float(r.y);
        bf16x4 v = *((const bf16x4*)(S + (size_t)r.x * D_DIM) + lane);
        acc[0] += wt * (float)v[0];
        acc[1] += wt * (float)v[1];
        acc[2] += wt * (float)v[2];
        acc[3] += wt * (float)v[3];
    }
    ((f32x4*)out)[(size_t)w * 64 + lane] = acc;
}

extern "C" void kernel_launch(void* const* d_in, const int* in_sizes, int n_in,
                              void* d_out, int out_size, void* d_ws, size_t ws_size,
                              hipStream_t stream) {
    const float* X     = (const float*)d_in[0];
    const int*   esrc  = (const int*)d_in[1];
    const int*   edst  = (const int*)d_in[2];
    const float* evals = (const float*)d_in[3];
    const float* W     = (const float*)d_in[4];
    const float* bias  = (const float*)d_in[5];
    float* out = (float*)d_out;

    const int N = in_sizes[0] / D_DIM;   // 100000
    const int E = in_sizes[1];           // 3200000

    // workspace carve-up (256B aligned)
    auto alignup = [](size_t x) { return (x + 255) & ~(size_t)255; };
    char* ws = (char*)d_ws;
    size_t o = 0;
    bf16* S      = (bf16*)(ws + o); o = alignup(o + (size_t)N * D_DIM * sizeof(bf16));
    int* counts  = (int*)(ws + o);  o = alignup(o + (size_t)N * sizeof(int));
    int* off     = (int*)(ws + o);  o = alignup(o + (size_t)N * sizeof(int));
    int* erank   = (int*)(ws + o);  o = alignup(o + (size_t)E * sizeof(int));
    int* bsums   = (int*)(ws + o);  o = alignup(o + 1024 * sizeof(int));
    int* bex     = (int*)(ws + o);  o = alignup(o + 1024 * sizeof(int));
    int2* eP     = (int2*)(ws + o); o = alignup(o + (size_t)E * sizeof(int2));
    bf16* Wf     = (bf16*)(ws + o); o = alignup(o + (size_t)D_DIM * D_DIM * sizeof(bf16));

    const int nb = (N + 1023) / 1024;        // 98 (<=128 required by scan_sums)
    const int nwaves = (N + 15) / 16;        // 6250

    hipMemsetAsync(counts, 0, (size_t)N * sizeof(int), stream);
    pack_w<<<128, 64, 0, stream>>>(W, Wf);
    gemm_xw<<<(nwaves + 3) / 4, 256, 0, stream>>>(X, Wf, S, N);
    rank_edges<<<2048, 256, 0, stream>>>(edst, counts, erank, E);
    scan_block<<<nb, 1024, 0, stream>>>(counts, N, off, bsums);
    scan_sums<<<1, 128, 0, stream>>>(bsums, nb, bex);
    add_base<<<nb, 1024, 0, stream>>>(off, bex, N);
    scatter_edges<<<2048, 256, 0, stream>>>(esrc, edst, evals, erank, off, eP, E);
    aggregate<<<(N + 3) / 4, 256, 0, stream>>>(S, off, counts, eP, bias, out, N);
}